// Round 1
// baseline (549.204 us; speedup 1.0000x reference)
//
#include <hip/hip_runtime.h>

typedef float f32x4_t __attribute__((ext_vector_type(4)));
typedef __bf16 bf16x8_t __attribute__((ext_vector_type(8)));
typedef unsigned short u16x8_t __attribute__((ext_vector_type(8)));

// ---- geometry ----
#define NPIX        100352      // 32*56*56
#define PIX_PER_IMG 3136        // 56*56
#define PH          58
#define PPIX        3364        // 58*58
#define C_IN        128
#define C_OUT       256
#define NTAPS       9
#define NV4         3211264     // x as float4 count (12845056/4)
#define NWELEM      294912      // 3*3*128*256
#define MBLK        784         // NPIX/128
#define NPADPIX     107648      // 32*58*58

// ---- ws byte offsets ----
#define OFF_ENC     0           // 2 x u32 (min/max encodings)
#define OFF_WQP     16          // wmn, wstep, wrstep (f32)
#define OFF_XQP     32          // xmn, xstep, xrstep (f32)
#define OFF_SCALE   64          // 256 f32
#define OFF_BIAS    1152        // 256 f32
#define OFF_WT      4096        // 589824 B bf16 [9][256][128]
#define OFF_WQT     593920      // 589824 B
#define OFF_PSUM    1183744     // 802816 B (1568*128 f32)
#define OFF_PSQ     1986560     // 802816 B
#define OFF_XPAD    2789376     // 27557888 B bf16 [32][58][58][128]
#define OFF_XQPAD   30347264    // 27557888 B   (end: 57905152)

// ---- helpers ----
__device__ __forceinline__ unsigned short f2bf(float x) {
  unsigned u = __float_as_uint(x);
  u += 0x7FFFu + ((u >> 16) & 1u);   // RNE
  return (unsigned short)(u >> 16);
}
__device__ __forceinline__ unsigned encf(float v) {
  unsigned u = __float_as_uint(v);
  return (u & 0x80000000u) ? ~u : (u | 0x80000000u);
}
__device__ __forceinline__ float decf(unsigned e) {
  unsigned u = (e & 0x80000000u) ? (e ^ 0x80000000u) : ~e;
  return __uint_as_float(u);
}
__device__ __forceinline__ void gl_lds16(const void* g, void* l) {
  auto gp = (const __attribute__((address_space(1))) unsigned*)(const unsigned*)g;
  auto lp = (__attribute__((address_space(3))) unsigned*)(unsigned*)l;
  __builtin_amdgcn_global_load_lds(gp, lp, 16, 0, 0);
}

// ---- kernels ----
__global__ void kinit(unsigned* enc) {
  enc[0] = 0xFFFFFFFFu;  // running-min encoding
  enc[1] = 0u;           // running-max encoding
}

__global__ void kminmax(const float4* __restrict__ x, unsigned* __restrict__ enc) {
  const int tid = blockIdx.x * blockDim.x + threadIdx.x;
  const int stride = gridDim.x * blockDim.x;
  float mn = 3.4e38f, mx = -3.4e38f;
  for (int i = tid; i < NV4; i += stride) {
    float4 v = x[i];
    mn = fminf(mn, fminf(fminf(v.x, v.y), fminf(v.z, v.w)));
    mx = fmaxf(mx, fmaxf(fmaxf(v.x, v.y), fmaxf(v.z, v.w)));
  }
  for (int off = 32; off > 0; off >>= 1) {
    mn = fminf(mn, __shfl_xor(mn, off));
    mx = fmaxf(mx, __shfl_xor(mx, off));
  }
  __shared__ float smn[4], smx[4];
  const int lane = threadIdx.x & 63, w = threadIdx.x >> 6;
  if (lane == 0) { smn[w] = mn; smx[w] = mx; }
  __syncthreads();
  if (threadIdx.x == 0) {
    mn = fminf(fminf(smn[0], smn[1]), fminf(smn[2], smn[3]));
    mx = fmaxf(fmaxf(smx[0], smx[1]), fmaxf(smx[2], smx[3]));
    atomicMin(&enc[0], encf(mn));
    atomicMax(&enc[1], encf(mx));
  }
}

__global__ void kprep(const unsigned* __restrict__ enc, float* __restrict__ xqp) {
  const float mn = decf(enc[0]), mx = decf(enc[1]);
  xqp[0] = mn;
  xqp[1] = (mx - mn) / 255.0f;
  xqp[2] = 255.0f / (mx - mn);
}

// W [3][3][128][256] f32 -> Wt [tap][256 f][128 c] bf16
__global__ void kwconv(const float* __restrict__ W, unsigned short* __restrict__ wt) {
  const int idx = blockIdx.x * 256 + threadIdx.x;
  if (idx >= NWELEM) return;
  const int c = idx & 127;
  const int f = (idx >> 7) & 255;
  const int tap = idx >> 15;
  wt[idx] = f2bf(W[(tap * 128 + c) * 256 + f]);
}

// quantized folded weights, same layout
__global__ void kwq(const float* __restrict__ W, const float* __restrict__ scale,
                    const float* __restrict__ wqp, unsigned short* __restrict__ wqt) {
  const int idx = blockIdx.x * 256 + threadIdx.x;
  if (idx >= NWELEM) return;
  const int c = idx & 127;
  const int f = (idx >> 7) & 255;
  const int tap = idx >> 15;
  const float wmn = wqp[0], wstep = wqp[1], wrstep = wqp[2];
  const float v = W[(tap * 128 + c) * 256 + f] * scale[f];
  const float q = rintf((v - wmn) * wrstep) * wstep + wmn;
  wqt[idx] = f2bf(q);
}

// pad-fill: x f32 -> xpad bf16 (zero border) and xqpad bf16 (quantized, zero border)
__global__ void kpadfill(const float* __restrict__ x, const float* __restrict__ xqp,
                         unsigned short* __restrict__ xpad, unsigned short* __restrict__ xqpad)
{
  const int tid = blockIdx.x * 256 + threadIdx.x;
  if (tid >= NPADPIX * 16) return;
  const int pp = tid >> 4;
  const int c8 = (tid & 15) << 3;
  const int n = pp / PPIX;
  const int rem = pp - n * PPIX;
  const int hp = rem / PH;
  const int wp = rem - hp * PH;
  u16x8_t vb, vq;
  #pragma unroll
  for (int j = 0; j < 8; ++j) { vb[j] = 0; vq[j] = 0; }
  if (hp >= 1 && hp <= 56 && wp >= 1 && wp <= 56) {
    const float mn = xqp[0], step = xqp[1], rstep = xqp[2];
    const float* src = x + ((n * PIX_PER_IMG) + (hp - 1) * 56 + (wp - 1)) * C_IN + c8;
    const float4 a = *(const float4*)src;
    const float4 b = *(const float4*)(src + 4);
    const float v[8] = {a.x, a.y, a.z, a.w, b.x, b.y, b.z, b.w};
    #pragma unroll
    for (int j = 0; j < 8; ++j) {
      vb[j] = f2bf(v[j]);
      const float qv = rintf((v[j] - mn) * rstep) * step + mn;
      vq[j] = f2bf(qv);
    }
  }
  *(u16x8_t*)(xpad + pp * C_IN + c8) = vb;
  *(u16x8_t*)(xqpad + pp * C_IN + c8) = vq;
}

// implicit-GEMM conv. STATS=1: emit per-block sum/sumsq partials. STATS=0: out = relu(conv + bias).
// Tile: 128 pixels (M) x 128 channels (N half, blockIdx.y) x K=9 taps * 128.
// 8 waves as 2(M)x4(N); wave tile 64x32; mfma 16x16x32 bf16.
template<int STATS>
__global__ __launch_bounds__(512, 4)
void kconv(const unsigned short* __restrict__ xin,   // padded bf16 [32][58][58][128]
           const unsigned short* __restrict__ wt,    // bf16 [9][256][128]
           float* __restrict__ out,
           const float* __restrict__ bias,
           float* __restrict__ psum,
           float* __restrict__ psq)
{
  const int bm = blockIdx.x;
  const int bn = blockIdx.y;
  const int tid = threadIdx.x;
  const int lane = tid & 63;
  const int wid = tid >> 6;
  const int wm = wid >> 2;
  const int wn = wid & 3;
  const int l16 = lane & 15;
  const int rsub = lane >> 4;

  __shared__ __align__(16) unsigned char smem[65536];
  unsigned char* smA = smem;            // 32 KiB: [128 rows(pix)][128 c] bf16, chunk-swizzled
  unsigned char* smB = smem + 32768;    // 32 KiB: [128 rows(f)  ][128 c] bf16, chunk-swizzled

  // --- staging addressing (global source pre-swizzled; LDS dest linear; read applies same XOR) ---
  const int rbase = wid * 4 + rsub;                       // row within 32-row round
  const int gchunk = (l16 & 8) | ((l16 & 7) ^ (rbase & 7));

  unsigned aoff[4];
  #pragma unroll
  for (int i = 0; i < 4; ++i) {
    const int pix = bm * 128 + i * 32 + rbase;
    const int n = pix / PIX_PER_IMG;
    const int rem = pix - n * PIX_PER_IMG;
    const int h = rem / 56;
    const int w = rem - h * 56;
    aoff[i] = (unsigned)((n * PPIX + h * PH + w) * C_IN + gchunk * 8);
  }
  unsigned boff[4];
  #pragma unroll
  for (int i = 0; i < 4; ++i) {
    const int f = bn * 128 + i * 32 + rbase;
    boff[i] = (unsigned)(f * C_IN + gchunk * 8);
  }

  f32x4_t acc[4][2];
  #pragma unroll
  for (int im = 0; im < 4; ++im)
    #pragma unroll
    for (int in = 0; in < 2; ++in)
      #pragma unroll
      for (int k = 0; k < 4; ++k) acc[im][in][k] = 0.f;

  #pragma unroll 1
  for (int tap = 0; tap < NTAPS; ++tap) {
    const int kh = tap / 3, kw = tap - kh * 3;
    const unsigned atap = (unsigned)((kh * PH + kw) * C_IN);
    const unsigned btap = (unsigned)(tap * C_OUT * C_IN);
    __syncthreads();   // previous tap's LDS reads complete before overwrite
    #pragma unroll
    for (int i = 0; i < 4; ++i)
      gl_lds16(xin + atap + aoff[i], smA + i * 8192 + wid * 1024);
    #pragma unroll
    for (int i = 0; i < 4; ++i)
      gl_lds16(wt + btap + boff[i], smB + i * 8192 + wid * 1024);
    __syncthreads();   // drain global_load_lds

    #pragma unroll
    for (int kb = 0; kb < 4; ++kb) {
      bf16x8_t av[4], bv[2];
      const int c = kb * 4 + rsub;
      const int p = (c & 8) | ((c & 7) ^ (l16 & 7));
      #pragma unroll
      for (int im = 0; im < 4; ++im) {
        const int row = wm * 64 + im * 16 + l16;
        av[im] = *(const bf16x8_t*)(smA + row * 256 + p * 16);
      }
      #pragma unroll
      for (int in = 0; in < 2; ++in) {
        const int row = wn * 32 + in * 16 + l16;
        bv[in] = *(const bf16x8_t*)(smB + row * 256 + p * 16);
      }
      #pragma unroll
      for (int im = 0; im < 4; ++im)
        #pragma unroll
        for (int in = 0; in < 2; ++in)
          acc[im][in] = __builtin_amdgcn_mfma_f32_16x16x32_bf16(av[im], bv[in], acc[im][in], 0, 0, 0);
    }
  }

  if (STATS) {
    __syncthreads();
    float* sb = (float*)smem;   // [8 waves][32 cols] sums, then sumsq at +256
    #pragma unroll
    for (int in = 0; in < 2; ++in) {
      float s = 0.f, q = 0.f;
      #pragma unroll
      for (int im = 0; im < 4; ++im)
        #pragma unroll
        for (int j = 0; j < 4; ++j) {
          const float v = acc[im][in][j];
          s += v; q += v * v;
        }
      s += __shfl_xor(s, 16); q += __shfl_xor(q, 16);
      s += __shfl_xor(s, 32); q += __shfl_xor(q, 32);
      if (lane < 16) {
        sb[wid * 32 + in * 16 + lane] = s;
        sb[256 + wid * 32 + in * 16 + lane] = q;
      }
    }
    __syncthreads();
    if (tid < 128) {
      const int wn2 = tid >> 5, cw = tid & 31;
      const float s = sb[wn2 * 32 + cw] + sb[(4 + wn2) * 32 + cw];
      const float q = sb[256 + wn2 * 32 + cw] + sb[256 + (4 + wn2) * 32 + cw];
      const int b = bm * 2 + bn;
      psum[b * 128 + tid] = s;
      psq[b * 128 + tid] = q;
    }
  } else {
    float bval[2];
    #pragma unroll
    for (int in = 0; in < 2; ++in)
      bval[in] = bias[bn * 128 + wn * 32 + in * 16 + l16];
    #pragma unroll
    for (int im = 0; im < 4; ++im) {
      #pragma unroll
      for (int j = 0; j < 4; ++j) {
        const int pix = bm * 128 + wm * 64 + im * 16 + rsub * 4 + j;
        #pragma unroll
        for (int in = 0; in < 2; ++in) {
          const int f = bn * 128 + wn * 32 + in * 16 + l16;
          out[pix * 256 + f] = fmaxf(acc[im][in][j] + bval[in], 0.f);
        }
      }
    }
  }
}

// finalize stats: mean/var/scale/bias + w_fold min/max + wstep
__global__ void kfinal(const float* __restrict__ psum, const float* __restrict__ psq,
                       const float* __restrict__ W, const float* __restrict__ gamma,
                       const float* __restrict__ beta, float* __restrict__ wqp,
                       float* __restrict__ scale, float* __restrict__ bias)
{
  const int ch = threadIdx.x;           // 256 threads
  const int bnn = ch >> 7, col = ch & 127;
  float s = 0.f, q = 0.f;
  for (int bm2 = 0; bm2 < MBLK; ++bm2) {
    const int b = bm2 * 2 + bnn;
    s += psum[b * 128 + col];
    q += psq[b * 128 + col];
  }
  const float inv = 1.0f / (float)NPIX;
  const float mean = s * inv;
  const float var = q * inv - mean * mean;
  const float istd = 1.0f / sqrtf(var + 1e-5f);
  const float sc = gamma[ch] * istd;
  scale[ch] = sc;
  bias[ch] = beta[ch] - gamma[ch] * mean * istd;

  __shared__ float scl[256];
  scl[ch] = sc;
  __syncthreads();
  float mn = 3.4e38f, mx = -3.4e38f;
  for (int idx = ch; idx < NWELEM; idx += 256) {
    const float v = W[idx] * scl[idx & 255];   // last dim of W is f (256)
    mn = fminf(mn, v); mx = fmaxf(mx, v);
  }
  for (int off = 32; off > 0; off >>= 1) {
    mn = fminf(mn, __shfl_xor(mn, off));
    mx = fmaxf(mx, __shfl_xor(mx, off));
  }
  __shared__ float rmn[4], rmx[4];
  const int lane = ch & 63, w = ch >> 6;
  if (lane == 0) { rmn[w] = mn; rmx[w] = mx; }
  __syncthreads();
  if (ch == 0) {
    mn = fminf(fminf(rmn[0], rmn[1]), fminf(rmn[2], rmn[3]));
    mx = fmaxf(fmaxf(rmx[0], rmx[1]), fmaxf(rmx[2], rmx[3]));
    wqp[0] = mn;
    wqp[1] = (mx - mn) / 255.0f;
    wqp[2] = 255.0f / (mx - mn);
  }
}

extern "C" void kernel_launch(void* const* d_in, const int* in_sizes, int n_in,
                              void* d_out, int out_size, void* d_ws, size_t ws_size,
                              hipStream_t stream)
{
  const float* x     = (const float*)d_in[0];
  const float* W     = (const float*)d_in[1];
  const float* gamma = (const float*)d_in[2];
  const float* beta  = (const float*)d_in[3];
  float* out = (float*)d_out;
  char* ws = (char*)d_ws;

  unsigned* enc        = (unsigned*)(ws + OFF_ENC);
  float* wqp           = (float*)(ws + OFF_WQP);
  float* xqp           = (float*)(ws + OFF_XQP);
  float* scale         = (float*)(ws + OFF_SCALE);
  float* bias          = (float*)(ws + OFF_BIAS);
  unsigned short* Wt   = (unsigned short*)(ws + OFF_WT);
  unsigned short* Wqt  = (unsigned short*)(ws + OFF_WQT);
  float* psum          = (float*)(ws + OFF_PSUM);
  float* psq           = (float*)(ws + OFF_PSQ);
  unsigned short* xpad  = (unsigned short*)(ws + OFF_XPAD);
  unsigned short* xqpad = (unsigned short*)(ws + OFF_XQPAD);

  kinit<<<1, 64, 0, stream>>>(enc);
  kminmax<<<1024, 256, 0, stream>>>((const float4*)x, enc);
  kprep<<<1, 64, 0, stream>>>(enc, xqp);
  kwconv<<<1152, 256, 0, stream>>>(W, Wt);
  kpadfill<<<6728, 256, 0, stream>>>(x, xqp, xpad, xqpad);
  kconv<1><<<dim3(MBLK, 2), 512, 0, stream>>>(xpad, Wt, nullptr, nullptr, psum, psq);
  kfinal<<<1, 256, 0, stream>>>(psum, psq, W, gamma, beta, wqp, scale, bias);
  kwq<<<1152, 256, 0, stream>>>(W, scale, wqp, Wqt);
  kconv<0><<<dim3(MBLK, 2), 512, 0, stream>>>(xqpad, Wqt, out, bias, nullptr, nullptr);
}

// Round 2
// 257.949 us; speedup vs baseline: 2.1291x; 2.1291x over previous
//
#include <hip/hip_runtime.h>

typedef float f32x4_t __attribute__((ext_vector_type(4)));
typedef __bf16 bf16x8_t __attribute__((ext_vector_type(8)));
typedef unsigned short u16x8_t __attribute__((ext_vector_type(8)));

// ---- geometry ----
#define NPIX        100352      // 32*56*56
#define PIX_PER_IMG 3136        // 56*56
#define PH          58
#define PPIX        3364        // 58*58
#define C_IN        128
#define C_OUT       256
#define NTAPS       9
#define NV4         3211264     // x as float4 count (12845056/4)
#define NWELEM      294912      // 3*3*128*256
#define MBLK        784         // NPIX/128
#define NPADPIX     107648      // 32*58*58

// ---- ws byte offsets ----
#define OFF_ENC     0           // 4 x u32 (x min/max, wfold min/max encodings)
#define OFF_WQP     16          // wmn, wstep, wrstep (f32)
#define OFF_XQP     32          // xmn, xstep, xrstep (f32)
#define OFF_SCALE   64          // 256 f32
#define OFF_BIAS    1152        // 256 f32
#define OFF_WT      4096        // 589824 B bf16 [9][256][128]
#define OFF_WQT     593920      // 589824 B
#define OFF_PSUM    1183744     // 802816 B (1568*128 f32)
#define OFF_PSQ     1986560     // 802816 B
#define OFF_XPAD    2789376     // 27557888 B bf16 [32][58][58][128]
#define OFF_XQPAD   30347264    // 27557888 B   (end: 57905152)

// ---- helpers ----
__device__ __forceinline__ unsigned short f2bf(float x) {
  unsigned u = __float_as_uint(x);
  u += 0x7FFFu + ((u >> 16) & 1u);   // RNE
  return (unsigned short)(u >> 16);
}
__device__ __forceinline__ unsigned encf(float v) {
  unsigned u = __float_as_uint(v);
  return (u & 0x80000000u) ? ~u : (u | 0x80000000u);
}
__device__ __forceinline__ float decf(unsigned e) {
  unsigned u = (e & 0x80000000u) ? (e ^ 0x80000000u) : ~e;
  return __uint_as_float(u);
}
__device__ __forceinline__ void gl_lds16(const void* g, void* l) {
  auto gp = (const __attribute__((address_space(1))) unsigned*)(const unsigned*)g;
  auto lp = (__attribute__((address_space(3))) unsigned*)(unsigned*)l;
  __builtin_amdgcn_global_load_lds(gp, lp, 16, 0, 0);
}

// ---- kernels ----
__global__ void kinit(unsigned* enc) {
  enc[0] = 0xFFFFFFFFu;  // x running-min encoding
  enc[1] = 0u;           // x running-max encoding
  enc[2] = 0xFFFFFFFFu;  // wfold running-min encoding
  enc[3] = 0u;           // wfold running-max encoding
}

__global__ void kminmax(const float4* __restrict__ x, unsigned* __restrict__ enc) {
  const int tid = blockIdx.x * blockDim.x + threadIdx.x;
  const int stride = gridDim.x * blockDim.x;
  float mn = 3.4e38f, mx = -3.4e38f;
  for (int i = tid; i < NV4; i += stride) {
    float4 v = x[i];
    mn = fminf(mn, fminf(fminf(v.x, v.y), fminf(v.z, v.w)));
    mx = fmaxf(mx, fmaxf(fmaxf(v.x, v.y), fmaxf(v.z, v.w)));
  }
  #pragma unroll
  for (int off = 32; off > 0; off >>= 1) {
    mn = fminf(mn, __shfl_xor(mn, off));
    mx = fmaxf(mx, __shfl_xor(mx, off));
  }
  __shared__ float smn[4], smx[4];
  const int lane = threadIdx.x & 63, w = threadIdx.x >> 6;
  if (lane == 0) { smn[w] = mn; smx[w] = mx; }
  __syncthreads();
  if (threadIdx.x == 0) {
    mn = fminf(fminf(smn[0], smn[1]), fminf(smn[2], smn[3]));
    mx = fmaxf(fmaxf(smx[0], smx[1]), fmaxf(smx[2], smx[3]));
    atomicMin(&enc[0], encf(mn));
    atomicMax(&enc[1], encf(mx));
  }
}

__global__ void kprep(const unsigned* __restrict__ enc, float* __restrict__ xqp) {
  const float mn = decf(enc[0]), mx = decf(enc[1]);
  xqp[0] = mn;
  xqp[1] = (mx - mn) / 255.0f;
  xqp[2] = 255.0f / (mx - mn);
}

// W [3][3][128][256] f32 -> Wt [tap][256 f][128 c] bf16
__global__ void kwconv(const float* __restrict__ W, unsigned short* __restrict__ wt) {
  const int idx = blockIdx.x * 256 + threadIdx.x;
  if (idx >= NWELEM) return;
  const int c = idx & 127;
  const int f = (idx >> 7) & 255;
  const int tap = idx >> 15;
  wt[idx] = f2bf(W[(tap * 128 + c) * 256 + f]);
}

// quantized folded weights, same layout
__global__ void kwq(const float* __restrict__ W, const float* __restrict__ scale,
                    const float* __restrict__ wqp, unsigned short* __restrict__ wqt) {
  const int idx = blockIdx.x * 256 + threadIdx.x;
  if (idx >= NWELEM) return;
  const int c = idx & 127;
  const int f = (idx >> 7) & 255;
  const int tap = idx >> 15;
  const float wmn = wqp[0], wstep = wqp[1], wrstep = wqp[2];
  const float v = W[(tap * 128 + c) * 256 + f] * scale[f];
  const float q = rintf((v - wmn) * wrstep) * wstep + wmn;
  wqt[idx] = f2bf(q);
}

// pad-fill: x f32 -> xpad bf16 (zero border) and xqpad bf16 (quantized, zero border)
__global__ void kpadfill(const float* __restrict__ x, const float* __restrict__ xqp,
                         unsigned short* __restrict__ xpad, unsigned short* __restrict__ xqpad)
{
  const int tid = blockIdx.x * 256 + threadIdx.x;
  if (tid >= NPADPIX * 16) return;
  const int pp = tid >> 4;
  const int c8 = (tid & 15) << 3;
  const int n = pp / PPIX;
  const int rem = pp - n * PPIX;
  const int hp = rem / PH;
  const int wp = rem - hp * PH;
  u16x8_t vb, vq;
  #pragma unroll
  for (int j = 0; j < 8; ++j) { vb[j] = 0; vq[j] = 0; }
  if (hp >= 1 && hp <= 56 && wp >= 1 && wp <= 56) {
    const float mn = xqp[0], step = xqp[1], rstep = xqp[2];
    const float* src = x + ((n * PIX_PER_IMG) + (hp - 1) * 56 + (wp - 1)) * C_IN + c8;
    const float4 a = *(const float4*)src;
    const float4 b = *(const float4*)(src + 4);
    const float v[8] = {a.x, a.y, a.z, a.w, b.x, b.y, b.z, b.w};
    #pragma unroll
    for (int j = 0; j < 8; ++j) {
      vb[j] = f2bf(v[j]);
      const float qv = rintf((v[j] - mn) * rstep) * step + mn;
      vq[j] = f2bf(qv);
    }
  }
  *(u16x8_t*)(xpad + pp * C_IN + c8) = vb;
  *(u16x8_t*)(xqpad + pp * C_IN + c8) = vq;
}

// implicit-GEMM conv. STATS=1: emit per-block sum/sumsq partials. STATS=0: out = relu(conv + bias).
template<int STATS>
__global__ __launch_bounds__(512, 4)
void kconv(const unsigned short* __restrict__ xin,   // padded bf16 [32][58][58][128]
           const unsigned short* __restrict__ wt,    // bf16 [9][256][128]
           float* __restrict__ out,
           const float* __restrict__ bias,
           float* __restrict__ psum,
           float* __restrict__ psq)
{
  const int bm = blockIdx.x;
  const int bn = blockIdx.y;
  const int tid = threadIdx.x;
  const int lane = tid & 63;
  const int wid = tid >> 6;
  const int wm = wid >> 2;
  const int wn = wid & 3;
  const int l16 = lane & 15;
  const int rsub = lane >> 4;

  __shared__ __align__(16) unsigned char smem[65536];
  unsigned char* smA = smem;            // 32 KiB: [128 rows(pix)][128 c] bf16, chunk-swizzled
  unsigned char* smB = smem + 32768;    // 32 KiB: [128 rows(f)  ][128 c] bf16, chunk-swizzled

  const int rbase = wid * 4 + rsub;                       // row within 32-row round
  const int gchunk = (l16 & 8) | ((l16 & 7) ^ (rbase & 7));

  unsigned aoff[4];
  #pragma unroll
  for (int i = 0; i < 4; ++i) {
    const int pix = bm * 128 + i * 32 + rbase;
    const int n = pix / PIX_PER_IMG;
    const int rem = pix - n * PIX_PER_IMG;
    const int h = rem / 56;
    const int w = rem - h * 56;
    aoff[i] = (unsigned)((n * PPIX + h * PH + w) * C_IN + gchunk * 8);
  }
  unsigned boff[4];
  #pragma unroll
  for (int i = 0; i < 4; ++i) {
    const int f = bn * 128 + i * 32 + rbase;
    boff[i] = (unsigned)(f * C_IN + gchunk * 8);
  }

  f32x4_t acc[4][2];
  #pragma unroll
  for (int im = 0; im < 4; ++im)
    #pragma unroll
    for (int in = 0; in < 2; ++in)
      #pragma unroll
      for (int k = 0; k < 4; ++k) acc[im][in][k] = 0.f;

  #pragma unroll 1
  for (int tap = 0; tap < NTAPS; ++tap) {
    const int kh = tap / 3, kw = tap - kh * 3;
    const unsigned atap = (unsigned)((kh * PH + kw) * C_IN);
    const unsigned btap = (unsigned)(tap * C_OUT * C_IN);
    __syncthreads();
    #pragma unroll
    for (int i = 0; i < 4; ++i)
      gl_lds16(xin + atap + aoff[i], smA + i * 8192 + wid * 1024);
    #pragma unroll
    for (int i = 0; i < 4; ++i)
      gl_lds16(wt + btap + boff[i], smB + i * 8192 + wid * 1024);
    __syncthreads();

    #pragma unroll
    for (int kb = 0; kb < 4; ++kb) {
      bf16x8_t av[4], bv[2];
      const int c = kb * 4 + rsub;
      const int p = (c & 8) | ((c & 7) ^ (l16 & 7));
      #pragma unroll
      for (int im = 0; im < 4; ++im) {
        const int row = wm * 64 + im * 16 + l16;
        av[im] = *(const bf16x8_t*)(smA + row * 256 + p * 16);
      }
      #pragma unroll
      for (int in = 0; in < 2; ++in) {
        const int row = wn * 32 + in * 16 + l16;
        bv[in] = *(const bf16x8_t*)(smB + row * 256 + p * 16);
      }
      #pragma unroll
      for (int im = 0; im < 4; ++im)
        #pragma unroll
        for (int in = 0; in < 2; ++in)
          acc[im][in] = __builtin_amdgcn_mfma_f32_16x16x32_bf16(av[im], bv[in], acc[im][in], 0, 0, 0);
    }
  }

  if (STATS) {
    __syncthreads();
    float* sb = (float*)smem;
    #pragma unroll
    for (int in = 0; in < 2; ++in) {
      float s = 0.f, q = 0.f;
      #pragma unroll
      for (int im = 0; im < 4; ++im)
        #pragma unroll
        for (int j = 0; j < 4; ++j) {
          const float v = acc[im][in][j];
          s += v; q += v * v;
        }
      s += __shfl_xor(s, 16); q += __shfl_xor(q, 16);
      s += __shfl_xor(s, 32); q += __shfl_xor(q, 32);
      if (lane < 16) {
        sb[wid * 32 + in * 16 + lane] = s;
        sb[256 + wid * 32 + in * 16 + lane] = q;
      }
    }
    __syncthreads();
    if (tid < 128) {
      const int wn2 = tid >> 5, cw = tid & 31;
      const float s = sb[wn2 * 32 + cw] + sb[(4 + wn2) * 32 + cw];
      const float q = sb[256 + wn2 * 32 + cw] + sb[256 + (4 + wn2) * 32 + cw];
      const int b = bm * 2 + bn;
      psum[b * 128 + tid] = s;
      psq[b * 128 + tid] = q;
    }
  } else {
    float bval[2];
    #pragma unroll
    for (int in = 0; in < 2; ++in)
      bval[in] = bias[bn * 128 + wn * 32 + in * 16 + l16];
    #pragma unroll
    for (int im = 0; im < 4; ++im) {
      #pragma unroll
      for (int j = 0; j < 4; ++j) {
        const int pix = bm * 128 + wm * 64 + im * 16 + rsub * 4 + j;
        #pragma unroll
        for (int in = 0; in < 2; ++in) {
          const int f = bn * 128 + wn * 32 + in * 16 + l16;
          out[pix * 256 + f] = fmaxf(acc[im][in][j] + bval[in], 0.f);
        }
      }
    }
  }
}

// per-channel stats: one block per channel
__global__ __launch_bounds__(256)
void kstats(const float* __restrict__ psum, const float* __restrict__ psq,
            const float* __restrict__ gamma, const float* __restrict__ beta,
            float* __restrict__ scale, float* __restrict__ bias)
{
  const int ch = blockIdx.x;
  const int bn = ch >> 7, col = ch & 127;
  float s = 0.f, q = 0.f;
  for (int bm = threadIdx.x; bm < MBLK; bm += 256) {
    const int b = bm * 2 + bn;
    s += psum[b * 128 + col];
    q += psq[b * 128 + col];
  }
  #pragma unroll
  for (int off = 32; off > 0; off >>= 1) {
    s += __shfl_xor(s, off);
    q += __shfl_xor(q, off);
  }
  __shared__ float ss[4], sq2[4];
  const int lane = threadIdx.x & 63, w = threadIdx.x >> 6;
  if (lane == 0) { ss[w] = s; sq2[w] = q; }
  __syncthreads();
  if (threadIdx.x == 0) {
    s = ss[0] + ss[1] + ss[2] + ss[3];
    q = sq2[0] + sq2[1] + sq2[2] + sq2[3];
    const float inv = 1.0f / (float)NPIX;
    const float mean = s * inv;
    const float var = q * inv - mean * mean;
    const float istd = 1.0f / sqrtf(var + 1e-5f);
    const float g = gamma[ch];
    scale[ch] = g * istd;
    bias[ch] = beta[ch] - g * mean * istd;
  }
}

// w_fold min/max, parallel over all elements
__global__ __launch_bounds__(256)
void kwmm(const float* __restrict__ W, const float* __restrict__ scale,
          unsigned* __restrict__ enc)
{
  const int idx = blockIdx.x * 256 + threadIdx.x;
  float v = 0.f;
  if (idx < NWELEM) v = W[idx] * scale[idx & 255];   // last dim of W is f (256)
  float mn = v, mx = v;
  #pragma unroll
  for (int off = 32; off > 0; off >>= 1) {
    mn = fminf(mn, __shfl_xor(mn, off));
    mx = fmaxf(mx, __shfl_xor(mx, off));
  }
  __shared__ float rmn[4], rmx[4];
  const int lane = threadIdx.x & 63, w = threadIdx.x >> 6;
  if (lane == 0) { rmn[w] = mn; rmx[w] = mx; }
  __syncthreads();
  if (threadIdx.x == 0) {
    mn = fminf(fminf(rmn[0], rmn[1]), fminf(rmn[2], rmn[3]));
    mx = fmaxf(fmaxf(rmx[0], rmx[1]), fmaxf(rmx[2], rmx[3]));
    atomicMin(&enc[2], encf(mn));
    atomicMax(&enc[3], encf(mx));
  }
}

__global__ void kwprep(const unsigned* __restrict__ enc, float* __restrict__ wqp) {
  const float mn = decf(enc[2]), mx = decf(enc[3]);
  wqp[0] = mn;
  wqp[1] = (mx - mn) / 255.0f;
  wqp[2] = 255.0f / (mx - mn);
}

extern "C" void kernel_launch(void* const* d_in, const int* in_sizes, int n_in,
                              void* d_out, int out_size, void* d_ws, size_t ws_size,
                              hipStream_t stream)
{
  const float* x     = (const float*)d_in[0];
  const float* W     = (const float*)d_in[1];
  const float* gamma = (const float*)d_in[2];
  const float* beta  = (const float*)d_in[3];
  float* out = (float*)d_out;
  char* ws = (char*)d_ws;

  unsigned* enc        = (unsigned*)(ws + OFF_ENC);
  float* wqp           = (float*)(ws + OFF_WQP);
  float* xqp           = (float*)(ws + OFF_XQP);
  float* scale         = (float*)(ws + OFF_SCALE);
  float* bias          = (float*)(ws + OFF_BIAS);
  unsigned short* Wt   = (unsigned short*)(ws + OFF_WT);
  unsigned short* Wqt  = (unsigned short*)(ws + OFF_WQT);
  float* psum          = (float*)(ws + OFF_PSUM);
  float* psq           = (float*)(ws + OFF_PSQ);
  unsigned short* xpad  = (unsigned short*)(ws + OFF_XPAD);
  unsigned short* xqpad = (unsigned short*)(ws + OFF_XQPAD);

  kinit<<<1, 64, 0, stream>>>(enc);
  kminmax<<<1024, 256, 0, stream>>>((const float4*)x, enc);
  kprep<<<1, 64, 0, stream>>>(enc, xqp);
  kwconv<<<1152, 256, 0, stream>>>(W, Wt);
  kpadfill<<<6728, 256, 0, stream>>>(x, xqp, xpad, xqpad);
  kconv<1><<<dim3(MBLK, 2), 512, 0, stream>>>(xpad, Wt, nullptr, nullptr, psum, psq);
  kstats<<<256, 256, 0, stream>>>(psum, psq, gamma, beta, scale, bias);
  kwmm<<<1152, 256, 0, stream>>>(W, scale, enc);
  kwprep<<<1, 64, 0, stream>>>(enc, wqp);
  kwq<<<1152, 256, 0, stream>>>(W, scale, wqp, Wqt);
  kconv<0><<<dim3(MBLK, 2), 512, 0, stream>>>(xqpad, Wqt, out, bias, nullptr, nullptr);
}

// Round 3
// 243.472 us; speedup vs baseline: 2.2557x; 1.0595x over previous
//
#include <hip/hip_runtime.h>

typedef float f32x4_t __attribute__((ext_vector_type(4)));
typedef __bf16 bf16x8_t __attribute__((ext_vector_type(8)));
typedef unsigned short u16x8_t __attribute__((ext_vector_type(8)));

// ---- geometry ----
#define NPIX        100352      // 32*56*56
#define PIX_PER_IMG 3136        // 56*56
#define PH          58
#define PPIX        3364        // 58*58
#define C_IN        128
#define C_OUT       256
#define NTAPS       9
#define NV4         3211264     // x as float4 count (12845056/4)
#define NWELEM      294912      // 3*3*128*256
#define MBLK2       392         // NPIX/256
#define NPADPIX     107648      // 32*58*58

// ---- ws byte offsets ----
#define OFF_ENC     0           // 4 x u32 (x min/max, wfold min/max encodings)
#define OFF_WQP     16          // wmn, wstep, wrstep (f32)
#define OFF_XQP     32          // xmn, xstep, xrstep (f32)
#define OFF_SCALE   64          // 256 f32
#define OFF_BIAS    1152        // 256 f32
#define OFF_WT      4096        // 589824 B bf16 [9][256][128]
#define OFF_WQT     593920      // 589824 B
#define OFF_PSUM    1183744     // (784*128 f32 used)
#define OFF_PSQ     1986560
#define OFF_XPAD    2789376     // 27557888 B bf16 [32][58][58][128]
#define OFF_XQPAD   30347264    // 27557888 B   (end: 57905152)

// ---- helpers ----
__device__ __forceinline__ unsigned short f2bf(float x) {
  unsigned u = __float_as_uint(x);
  u += 0x7FFFu + ((u >> 16) & 1u);   // RNE
  return (unsigned short)(u >> 16);
}
__device__ __forceinline__ unsigned encf(float v) {
  unsigned u = __float_as_uint(v);
  return (u & 0x80000000u) ? ~u : (u | 0x80000000u);
}
__device__ __forceinline__ float decf(unsigned e) {
  unsigned u = (e & 0x80000000u) ? (e ^ 0x80000000u) : ~e;
  return __uint_as_float(u);
}
__device__ __forceinline__ void gl_lds16(const void* g, void* l) {
  auto gp = (const __attribute__((address_space(1))) unsigned*)(const unsigned*)g;
  auto lp = (__attribute__((address_space(3))) unsigned*)(unsigned*)l;
  __builtin_amdgcn_global_load_lds(gp, lp, 16, 0, 0);
}

// ---- kernels ----
__global__ void kinit(unsigned* enc) {
  enc[0] = 0xFFFFFFFFu;  // x running-min encoding
  enc[1] = 0u;           // x running-max encoding
  enc[2] = 0xFFFFFFFFu;  // wfold running-min encoding
  enc[3] = 0u;           // wfold running-max encoding
}

__global__ void kminmax(const float4* __restrict__ x, unsigned* __restrict__ enc) {
  const int tid = blockIdx.x * blockDim.x + threadIdx.x;
  const int stride = gridDim.x * blockDim.x;
  float mn = 3.4e38f, mx = -3.4e38f;
  for (int i = tid; i < NV4; i += stride) {
    float4 v = x[i];
    mn = fminf(mn, fminf(fminf(v.x, v.y), fminf(v.z, v.w)));
    mx = fmaxf(mx, fmaxf(fmaxf(v.x, v.y), fmaxf(v.z, v.w)));
  }
  #pragma unroll
  for (int off = 32; off > 0; off >>= 1) {
    mn = fminf(mn, __shfl_xor(mn, off));
    mx = fmaxf(mx, __shfl_xor(mx, off));
  }
  __shared__ float smn[4], smx[4];
  const int lane = threadIdx.x & 63, w = threadIdx.x >> 6;
  if (lane == 0) { smn[w] = mn; smx[w] = mx; }
  __syncthreads();
  if (threadIdx.x == 0) {
    mn = fminf(fminf(smn[0], smn[1]), fminf(smn[2], smn[3]));
    mx = fmaxf(fmaxf(smx[0], smx[1]), fmaxf(smx[2], smx[3]));
    atomicMin(&enc[0], encf(mn));
    atomicMax(&enc[1], encf(mx));
  }
}

__global__ void kprep(const unsigned* __restrict__ enc, float* __restrict__ xqp) {
  const float mn = decf(enc[0]), mx = decf(enc[1]);
  xqp[0] = mn;
  xqp[1] = (mx - mn) / 255.0f;
  xqp[2] = 255.0f / (mx - mn);
}

// W [3][3][128][256] f32 -> Wt [tap][256 f][128 c] bf16
__global__ void kwconv(const float* __restrict__ W, unsigned short* __restrict__ wt) {
  const int idx = blockIdx.x * 256 + threadIdx.x;
  if (idx >= NWELEM) return;
  const int c = idx & 127;
  const int f = (idx >> 7) & 255;
  const int tap = idx >> 15;
  wt[idx] = f2bf(W[(tap * 128 + c) * 256 + f]);
}

// quantized folded weights, same layout
__global__ void kwq(const float* __restrict__ W, const float* __restrict__ scale,
                    const float* __restrict__ wqp, unsigned short* __restrict__ wqt) {
  const int idx = blockIdx.x * 256 + threadIdx.x;
  if (idx >= NWELEM) return;
  const int c = idx & 127;
  const int f = (idx >> 7) & 255;
  const int tap = idx >> 15;
  const float wmn = wqp[0], wstep = wqp[1], wrstep = wqp[2];
  const float v = W[(tap * 128 + c) * 256 + f] * scale[f];
  const float q = rintf((v - wmn) * wrstep) * wstep + wmn;
  wqt[idx] = f2bf(q);
}

// pad-fill: x f32 -> xpad bf16 (zero border) and xqpad bf16 (quantized, zero border)
__global__ void kpadfill(const float* __restrict__ x, const float* __restrict__ xqp,
                         unsigned short* __restrict__ xpad, unsigned short* __restrict__ xqpad)
{
  const int tid = blockIdx.x * 256 + threadIdx.x;
  if (tid >= NPADPIX * 16) return;
  const int pp = tid >> 4;
  const int c8 = (tid & 15) << 3;
  const int n = pp / PPIX;
  const int rem = pp - n * PPIX;
  const int hp = rem / PH;
  const int wp = rem - hp * PH;
  u16x8_t vb, vq;
  #pragma unroll
  for (int j = 0; j < 8; ++j) { vb[j] = 0; vq[j] = 0; }
  if (hp >= 1 && hp <= 56 && wp >= 1 && wp <= 56) {
    const float mn = xqp[0], step = xqp[1], rstep = xqp[2];
    const float* src = x + ((n * PIX_PER_IMG) + (hp - 1) * 56 + (wp - 1)) * C_IN + c8;
    const float4 a = *(const float4*)src;
    const float4 b = *(const float4*)(src + 4);
    const float v[8] = {a.x, a.y, a.z, a.w, b.x, b.y, b.z, b.w};
    #pragma unroll
    for (int j = 0; j < 8; ++j) {
      vb[j] = f2bf(v[j]);
      const float qv = rintf((v[j] - mn) * rstep) * step + mn;
      vq[j] = f2bf(qv);
    }
  }
  *(u16x8_t*)(xpad + pp * C_IN + c8) = vb;
  *(u16x8_t*)(xqpad + pp * C_IN + c8) = vq;
}

// implicit-GEMM conv, 256x128 tile, BK=64 (half tap), double-buffered 2-phase pipeline.
// 8 waves as 4(M)x2(N); wave tile 64x64; mfma 16x16x32 bf16.
// STATS=1: per-block column sum/sumsq partials. STATS=0: out = relu(conv + bias).
template<int STATS>
__global__ __launch_bounds__(512, 2)
void kconv(const unsigned short* __restrict__ xin,   // padded bf16 [32][58][58][128]
           const unsigned short* __restrict__ wt,    // bf16 [9][256][128]
           float* __restrict__ out,
           const float* __restrict__ bias,
           float* __restrict__ psum,
           float* __restrict__ psq)
{
  // XCD-aware decode: pair (bm,0)/(bm,1) lands on the same XCD (assumes l%8 XCD round-robin;
  // wrong assumption only costs locality, never correctness). Bijective: 8 XCDs x 98 slots.
  const int l = blockIdx.x;            // 0..783
  const int xcd = l & 7, k = l >> 3;   // k: 0..97
  const int bn = k & 1;
  const int bm = xcd * 49 + (k >> 1);  // 0..391

  const int tid = threadIdx.x;
  const int lane = tid & 63;
  const int wid = tid >> 6;
  const int wm = wid >> 1;          // 0..3
  const int wn = wid & 1;           // 0..1
  const int l16 = lane & 15;
  const int rsub = lane >> 4;

  __shared__ __align__(16) unsigned char smem[98304];   // 2 x (A 32K + B 16K)

  // staging source offsets (elements). LDS dest is linear; global source pre-swizzled
  // with chunk ^= (row&7) so swizzled reads see logical channel order (rule #21).
  const int lrow = lane >> 3;                 // row within wave's 8-row slab (== LDS row & 7)
  const int lchunk = (lane & 7) ^ lrow;       // logical chunk for this phys slot
  unsigned aoff[4];
  #pragma unroll
  for (int r = 0; r < 4; ++r) {
    const int pix = bm * 256 + r * 64 + wid * 8 + lrow;
    const int n = pix / PIX_PER_IMG;
    const int rem = pix - n * PIX_PER_IMG;
    const int hh = rem / 56;
    const int ww = rem - hh * 56;
    aoff[r] = (unsigned)((n * PPIX + hh * PH + ww) * C_IN + lchunk * 8);
  }
  unsigned boff[2];
  #pragma unroll
  for (int r = 0; r < 2; ++r) {
    const int f = bn * 128 + r * 64 + wid * 8 + lrow;
    boff[r] = (unsigned)(f * C_IN + lchunk * 8);
  }

  f32x4_t acc[4][4];
  #pragma unroll
  for (int im = 0; im < 4; ++im)
    #pragma unroll
    for (int in = 0; in < 4; ++in)
      #pragma unroll
      for (int j = 0; j < 4; ++j) acc[im][in][j] = 0.f;

  auto stage = [&](int bsel, int s) {
    const int tap = s >> 1, h = (s & 1) << 6;          // half: +0 / +64 channels
    const int kh = tap / 3, kw = tap - kh * 3;
    const unsigned atap = (unsigned)((kh * PH + kw) * C_IN + h);
    const unsigned btap = (unsigned)(tap * C_OUT * C_IN + h);
    unsigned char* sA = smem + bsel * 49152;
    unsigned char* sB = sA + 32768;
    #pragma unroll
    for (int r = 0; r < 4; ++r)
      gl_lds16(xin + atap + aoff[r], sA + r * 8192 + wid * 1024);
    #pragma unroll
    for (int r = 0; r < 2; ++r)
      gl_lds16(wt + btap + boff[r], sB + r * 8192 + wid * 1024);
  };

  stage(0, 0);
  __syncthreads();            // prologue drain (vmcnt0 + barrier)
  int cur = 0;

  #pragma unroll 1
  for (int s = 0; s < 18; ++s) {
    if (s < 17) stage(cur ^ 1, s + 1);      // prefetch next K-step; lands during compute
    const unsigned char* sA = smem + cur * 49152;
    const unsigned char* sB = sA + 32768;
    #pragma unroll
    for (int kb = 0; kb < 2; ++kb) {
      const int c = kb * 4 + rsub;          // K-chunk (8 bf16) index, 0..7
      const int p = c ^ (l16 & 7);          // swizzled phys chunk (row&7 == l16&7)
      bf16x8_t av[4], bv[4];
      #pragma unroll
      for (int im = 0; im < 4; ++im)
        av[im] = *(const bf16x8_t*)(sA + (wm * 64 + im * 16 + l16) * 128 + p * 16);
      #pragma unroll
      for (int in = 0; in < 4; ++in)
        bv[in] = *(const bf16x8_t*)(sB + (wn * 64 + in * 16 + l16) * 128 + p * 16);
      #pragma unroll
      for (int im = 0; im < 4; ++im)
        #pragma unroll
        for (int in = 0; in < 4; ++in)
          acc[im][in] = __builtin_amdgcn_mfma_f32_16x16x32_bf16(av[im], bv[in], acc[im][in], 0, 0, 0);
    }
    __syncthreads();          // drains prefetch (had whole compute phase to land) + buffer swap
    cur ^= 1;
  }

  if (STATS) {
    float* sb = (float*)smem;      // [8 waves][64 cols]
    #pragma unroll
    for (int in = 0; in < 4; ++in) {
      float s = 0.f, q = 0.f;
      #pragma unroll
      for (int im = 0; im < 4; ++im)
        #pragma unroll
        for (int j = 0; j < 4; ++j) {
          const float v = acc[im][in][j];
          s += v; q += v * v;
        }
      s += __shfl_xor(s, 16); q += __shfl_xor(q, 16);
      s += __shfl_xor(s, 32); q += __shfl_xor(q, 32);
      if (lane < 16) {
        sb[wid * 64 + in * 16 + lane] = s;
        sb[512 + wid * 64 + in * 16 + lane] = q;
      }
    }
    __syncthreads();
    if (tid < 128) {
      const int wn2 = tid >> 6, cl = tid & 63;
      float s = 0.f, q = 0.f;
      #pragma unroll
      for (int wm2 = 0; wm2 < 4; ++wm2) {
        s += sb[(wm2 * 2 + wn2) * 64 + cl];
        q += sb[512 + (wm2 * 2 + wn2) * 64 + cl];
      }
      const int b = bm * 2 + bn;
      psum[b * 128 + tid] = s;
      psq[b * 128 + tid] = q;
    }
  } else {
    float bval[4];
    #pragma unroll
    for (int in = 0; in < 4; ++in)
      bval[in] = bias[bn * 128 + wn * 64 + in * 16 + l16];
    #pragma unroll
    for (int im = 0; im < 4; ++im) {
      #pragma unroll
      for (int j = 0; j < 4; ++j) {
        const int pix = bm * 256 + wm * 64 + im * 16 + rsub * 4 + j;
        #pragma unroll
        for (int in = 0; in < 4; ++in) {
          const int f = bn * 128 + wn * 64 + in * 16 + l16;
          out[pix * 256 + f] = fmaxf(acc[im][in][j] + bval[in], 0.f);
        }
      }
    }
  }
}

// per-channel stats: one block per channel
__global__ __launch_bounds__(256)
void kstats(const float* __restrict__ psum, const float* __restrict__ psq,
            const float* __restrict__ gamma, const float* __restrict__ beta,
            float* __restrict__ scale, float* __restrict__ bias)
{
  const int ch = blockIdx.x;
  const int bn = ch >> 7, col = ch & 127;
  float s = 0.f, q = 0.f;
  for (int bm = threadIdx.x; bm < MBLK2; bm += 256) {
    const int b = bm * 2 + bn;
    s += psum[b * 128 + col];
    q += psq[b * 128 + col];
  }
  #pragma unroll
  for (int off = 32; off > 0; off >>= 1) {
    s += __shfl_xor(s, off);
    q += __shfl_xor(q, off);
  }
  __shared__ float ss[4], sq2[4];
  const int lane = threadIdx.x & 63, w = threadIdx.x >> 6;
  if (lane == 0) { ss[w] = s; sq2[w] = q; }
  __syncthreads();
  if (threadIdx.x == 0) {
    s = ss[0] + ss[1] + ss[2] + ss[3];
    q = sq2[0] + sq2[1] + sq2[2] + sq2[3];
    const float inv = 1.0f / (float)NPIX;
    const float mean = s * inv;
    const float var = q * inv - mean * mean;
    const float istd = 1.0f / sqrtf(var + 1e-5f);
    const float g = gamma[ch];
    scale[ch] = g * istd;
    bias[ch] = beta[ch] - g * mean * istd;
  }
}

// w_fold min/max, parallel over all elements
__global__ __launch_bounds__(256)
void kwmm(const float* __restrict__ W, const float* __restrict__ scale,
          unsigned* __restrict__ enc)
{
  const int idx = blockIdx.x * 256 + threadIdx.x;
  float v = 0.f;
  if (idx < NWELEM) v = W[idx] * scale[idx & 255];   // last dim of W is f (256)
  float mn = v, mx = v;
  #pragma unroll
  for (int off = 32; off > 0; off >>= 1) {
    mn = fminf(mn, __shfl_xor(mn, off));
    mx = fmaxf(mx, __shfl_xor(mx, off));
  }
  __shared__ float rmn[4], rmx[4];
  const int lane = threadIdx.x & 63, w = threadIdx.x >> 6;
  if (lane == 0) { rmn[w] = mn; rmx[w] = mx; }
  __syncthreads();
  if (threadIdx.x == 0) {
    mn = fminf(fminf(rmn[0], rmn[1]), fminf(rmn[2], rmn[3]));
    mx = fmaxf(fmaxf(rmx[0], rmx[1]), fmaxf(rmx[2], rmx[3]));
    atomicMin(&enc[2], encf(mn));
    atomicMax(&enc[3], encf(mx));
  }
}

__global__ void kwprep(const unsigned* __restrict__ enc, float* __restrict__ wqp) {
  const float mn = decf(enc[2]), mx = decf(enc[3]);
  wqp[0] = mn;
  wqp[1] = (mx - mn) / 255.0f;
  wqp[2] = 255.0f / (mx - mn);
}

extern "C" void kernel_launch(void* const* d_in, const int* in_sizes, int n_in,
                              void* d_out, int out_size, void* d_ws, size_t ws_size,
                              hipStream_t stream)
{
  const float* x     = (const float*)d_in[0];
  const float* W     = (const float*)d_in[1];
  const float* gamma = (const float*)d_in[2];
  const float* beta  = (const float*)d_in[3];
  float* out = (float*)d_out;
  char* ws = (char*)d_ws;

  unsigned* enc        = (unsigned*)(ws + OFF_ENC);
  float* wqp           = (float*)(ws + OFF_WQP);
  float* xqp           = (float*)(ws + OFF_XQP);
  float* scale         = (float*)(ws + OFF_SCALE);
  float* bias          = (float*)(ws + OFF_BIAS);
  unsigned short* Wt   = (unsigned short*)(ws + OFF_WT);
  unsigned short* Wqt  = (unsigned short*)(ws + OFF_WQT);
  float* psum          = (float*)(ws + OFF_PSUM);
  float* psq           = (float*)(ws + OFF_PSQ);
  unsigned short* xpad  = (unsigned short*)(ws + OFF_XPAD);
  unsigned short* xqpad = (unsigned short*)(ws + OFF_XQPAD);

  kinit<<<1, 64, 0, stream>>>(enc);
  kminmax<<<1024, 256, 0, stream>>>((const float4*)x, enc);
  kprep<<<1, 64, 0, stream>>>(enc, xqp);
  kwconv<<<1152, 256, 0, stream>>>(W, Wt);
  kpadfill<<<6728, 256, 0, stream>>>(x, xqp, xpad, xqpad);
  kconv<1><<<784, 512, 0, stream>>>(xpad, Wt, nullptr, nullptr, psum, psq);
  kstats<<<256, 256, 0, stream>>>(psum, psq, gamma, beta, scale, bias);
  kwmm<<<1152, 256, 0, stream>>>(W, scale, enc);
  kwprep<<<1, 64, 0, stream>>>(enc, wqp);
  kwq<<<1152, 256, 0, stream>>>(W, scale, wqp, Wqt);
  kconv<0><<<784, 512, 0, stream>>>(xqpad, Wqt, out, bias, nullptr, nullptr);
}

// Round 4
// 230.363 us; speedup vs baseline: 2.3841x; 1.0569x over previous
//
#include <hip/hip_runtime.h>

typedef float f32x4_t __attribute__((ext_vector_type(4)));
typedef __bf16 bf16x8_t __attribute__((ext_vector_type(8)));
typedef unsigned short u16x8_t __attribute__((ext_vector_type(8)));

// ---- geometry ----
#define NPIX        100352      // 32*56*56
#define PIX_PER_IMG 3136        // 56*56
#define PH          58
#define PPIX        3364        // 58*58
#define C_IN        128
#define C_OUT       256
#define NTAPS       9
#define NV4         3211264     // x as float4 count
#define NWELEM      294912      // 3*3*128*256
#define MTILES      392         // NPIX/256
#define NPADPIX     107648      // 32*58*58

// ---- ws byte offsets ----
#define OFF_ENC     0           // 4 x u32 (x min/max, wfold min/max encodings)
#define OFF_SCALE   64          // 256 f32
#define OFF_BIAS    1152        // 256 f32
#define OFF_WT      4096        // 589824 B bf16 [9][256][128]
#define OFF_WQT     593920      // 589824 B
#define OFF_PSUM    1183744     // 392*256 f32 = 401408 B
#define OFF_PSQ     1986560     // 392*256 f32
#define OFF_XPAD    2789376     // 27557888 B bf16 [32][58][58][128]
#define OFF_XQPAD   30347264    // 27557888 B   (end: 57905152)

// ---- helpers ----
__device__ __forceinline__ unsigned short f2bf(float x) {
  unsigned u = __float_as_uint(x);
  u += 0x7FFFu + ((u >> 16) & 1u);   // RNE
  return (unsigned short)(u >> 16);
}
__device__ __forceinline__ unsigned encf(float v) {
  unsigned u = __float_as_uint(v);
  return (u & 0x80000000u) ? ~u : (u | 0x80000000u);
}
__device__ __forceinline__ float decf(unsigned e) {
  unsigned u = (e & 0x80000000u) ? (e ^ 0x80000000u) : ~e;
  return __uint_as_float(u);
}
__device__ __forceinline__ void gl_lds16(const void* g, void* l) {
  auto gp = (const __attribute__((address_space(1))) unsigned*)(const unsigned*)g;
  auto lp = (__attribute__((address_space(3))) unsigned*)(unsigned*)l;
  __builtin_amdgcn_global_load_lds(gp, lp, 16, 0, 0);
}
#define SCHED_FENCE() __builtin_amdgcn_sched_barrier(0)

// ---- kernels ----
__global__ void kinit(unsigned* enc) {
  enc[0] = 0xFFFFFFFFu;  // x running-min encoding
  enc[1] = 0u;           // x running-max encoding
  enc[2] = 0xFFFFFFFFu;  // wfold running-min encoding
  enc[3] = 0u;           // wfold running-max encoding
}

__global__ void kminmax(const float4* __restrict__ x, unsigned* __restrict__ enc) {
  const int tid = blockIdx.x * blockDim.x + threadIdx.x;
  const int stride = gridDim.x * blockDim.x;
  float mn = 3.4e38f, mx = -3.4e38f;
  for (int i = tid; i < NV4; i += stride) {
    float4 v = x[i];
    mn = fminf(mn, fminf(fminf(v.x, v.y), fminf(v.z, v.w)));
    mx = fmaxf(mx, fmaxf(fmaxf(v.x, v.y), fmaxf(v.z, v.w)));
  }
  #pragma unroll
  for (int off = 32; off > 0; off >>= 1) {
    mn = fminf(mn, __shfl_xor(mn, off));
    mx = fmaxf(mx, __shfl_xor(mx, off));
  }
  __shared__ float smn[4], smx[4];
  const int lane = threadIdx.x & 63, w = threadIdx.x >> 6;
  if (lane == 0) { smn[w] = mn; smx[w] = mx; }
  __syncthreads();
  if (threadIdx.x == 0) {
    mn = fminf(fminf(smn[0], smn[1]), fminf(smn[2], smn[3]));
    mx = fmaxf(fmaxf(smx[0], smx[1]), fmaxf(smx[2], smx[3]));
    atomicMin(&enc[0], encf(mn));
    atomicMax(&enc[1], encf(mx));
  }
}

// W [3][3][128][256] f32 -> Wt [tap][256 f][128 c] bf16
__global__ void kwconv(const float* __restrict__ W, unsigned short* __restrict__ wt) {
  const int idx = blockIdx.x * 256 + threadIdx.x;
  if (idx >= NWELEM) return;
  const int c = idx & 127;
  const int f = (idx >> 7) & 255;
  const int tap = idx >> 15;
  wt[idx] = f2bf(W[(tap * 128 + c) * 256 + f]);
}

// quantized folded weights, same layout (reads wfold min/max from enc directly)
__global__ void kwq(const float* __restrict__ W, const float* __restrict__ scale,
                    const unsigned* __restrict__ enc, unsigned short* __restrict__ wqt) {
  const int idx = blockIdx.x * 256 + threadIdx.x;
  if (idx >= NWELEM) return;
  const int c = idx & 127;
  const int f = (idx >> 7) & 255;
  const int tap = idx >> 15;
  const float wmn = decf(enc[2]), wmx = decf(enc[3]);
  const float wstep = (wmx - wmn) / 255.0f;
  const float wrstep = 255.0f / (wmx - wmn);
  const float v = W[(tap * 128 + c) * 256 + f] * scale[f];
  const float q = rintf((v - wmn) * wrstep) * wstep + wmn;
  wqt[idx] = f2bf(q);
}

// pad-fill: x f32 -> xpad bf16 (zero border) and xqpad bf16 (quantized, zero border)
__global__ void kpadfill(const float* __restrict__ x, const unsigned* __restrict__ enc,
                         unsigned short* __restrict__ xpad, unsigned short* __restrict__ xqpad)
{
  const int tid = blockIdx.x * 256 + threadIdx.x;
  if (tid >= NPADPIX * 16) return;
  const int pp = tid >> 4;
  const int c8 = (tid & 15) << 3;
  const int n = pp / PPIX;
  const int rem = pp - n * PPIX;
  const int hp = rem / PH;
  const int wp = rem - hp * PH;
  u16x8_t vb, vq;
  #pragma unroll
  for (int j = 0; j < 8; ++j) { vb[j] = 0; vq[j] = 0; }
  if (hp >= 1 && hp <= 56 && wp >= 1 && wp <= 56) {
    const float mn = decf(enc[0]), mx = decf(enc[1]);
    const float step = (mx - mn) / 255.0f, rstep = 255.0f / (mx - mn);
    const float* src = x + ((n * PIX_PER_IMG) + (hp - 1) * 56 + (wp - 1)) * C_IN + c8;
    const float4 a = *(const float4*)src;
    const float4 b = *(const float4*)(src + 4);
    const float v[8] = {a.x, a.y, a.z, a.w, b.x, b.y, b.z, b.w};
    #pragma unroll
    for (int j = 0; j < 8; ++j) {
      vb[j] = f2bf(v[j]);
      const float qv = rintf((v[j] - mn) * rstep) * step + mn;
      vq[j] = f2bf(qv);
    }
  }
  *(u16x8_t*)(xpad + pp * C_IN + c8) = vb;
  *(u16x8_t*)(xqpad + pp * C_IN + c8) = vq;
}

// implicit-GEMM conv, 256x256 tile (BN = full C_OUT), BK=64, double-buffered with
// counted vmcnt (never 0 in main loop). 8 waves as 2(M)x4(N); wave tile 128x64.
// 18 K-tiles = 9 taps x 2 channel-halves.
// STATS=1: per-block column sum/sumsq partials. STATS=0: out = relu(conv + bias).
template<int STATS>
__global__ __launch_bounds__(512, 2)
void kconv(const unsigned short* __restrict__ xin,   // padded bf16 [32][58][58][128]
           const unsigned short* __restrict__ wt,    // bf16 [9][256][128]
           float* __restrict__ out,
           const float* __restrict__ bias,
           float* __restrict__ psum,
           float* __restrict__ psq)
{
  // XCD-aware bijective swizzle (392 = 8*49): consecutive bm share halo rows per XCD.
  const int bid = blockIdx.x;
  const int bm = (bid & 7) * 49 + (bid >> 3);      // 0..391

  const int tid = threadIdx.x;
  const int lane = tid & 63;
  const int wid = tid >> 6;
  const int wm = wid >> 2;          // 0..1
  const int wn = wid & 3;           // 0..3
  const int l16 = lane & 15;
  const int rsub = lane >> 4;

  __shared__ __align__(16) unsigned char smem[131072];   // 2 x (A 32K + B 32K)

  // constant-per-thread logical chunk (XOR swizzle, rule #21: pre-swizzled global src,
  // linear global_load_lds dest, swizzled ds_read)
  const int lchunk = (tid & 7) ^ ((tid >> 3) & 7);

  unsigned aoff[4];
  #pragma unroll
  for (int j = 0; j < 4; ++j) {
    const int pix = bm * 256 + j * 64 + (tid >> 3);
    const int n = pix / PIX_PER_IMG;
    const int rem = pix - n * PIX_PER_IMG;
    const int hh = rem / 56;
    const int ww = rem - hh * 56;
    aoff[j] = (unsigned)((n * PPIX + hh * PH + ww) * C_IN + lchunk * 8);
  }
  unsigned boff[4];
  #pragma unroll
  for (int j = 0; j < 4; ++j) {
    const int f = j * 64 + (tid >> 3);
    boff[j] = (unsigned)(f * C_IN + lchunk * 8);
  }

  f32x4_t acc[8][4];
  #pragma unroll
  for (int im = 0; im < 8; ++im)
    #pragma unroll
    for (int in = 0; in < 4; ++in)
      #pragma unroll
      for (int j = 0; j < 4; ++j) acc[im][in][j] = 0.f;

  // stage K-tile s into buffer bsel (8 global_load_lds per thread; dest is wave-uniform
  // base, HW adds lane*16)
  auto stage = [&](int bsel, int s) {
    const int tap = s >> 1;
    const int chalf = (s & 1) << 6;
    const int kh = tap / 3, kw = tap - kh * 3;
    const unsigned atap = (unsigned)((kh * PH + kw) * C_IN + chalf);
    const unsigned btap = (unsigned)(tap * C_OUT * C_IN + chalf);
    unsigned char* sA = smem + bsel * 65536;
    unsigned char* sB = sA + 32768;
    #pragma unroll
    for (int j = 0; j < 4; ++j)
      gl_lds16(xin + atap + aoff[j], sA + j * 8192 + wid * 1024);
    #pragma unroll
    for (int j = 0; j < 4; ++j)
      gl_lds16(wt + btap + boff[j], sB + j * 8192 + wid * 1024);
  };

  auto compute = [&](int bsel) {
    const unsigned char* sA = smem + bsel * 65536;
    const unsigned char* sB = sA + 32768;
    #pragma unroll
    for (int ks = 0; ks < 2; ++ks) {
      const int c = ks * 4 + rsub;          // K-chunk index 0..7
      const int p = c ^ (l16 & 7);          // swizzled phys chunk
      bf16x8_t av[8], bv[4];
      #pragma unroll
      for (int im = 0; im < 8; ++im)
        av[im] = *(const bf16x8_t*)(sA + (wm * 128 + im * 16 + l16) * 128 + p * 16);
      #pragma unroll
      for (int in = 0; in < 4; ++in)
        bv[in] = *(const bf16x8_t*)(sB + (wn * 64 + in * 16 + l16) * 128 + p * 16);
      #pragma unroll
      for (int im = 0; im < 8; ++im)
        #pragma unroll
        for (int in = 0; in < 4; ++in)
          acc[im][in] = __builtin_amdgcn_mfma_f32_16x16x32_bf16(av[im], bv[in], acc[im][in], 0, 0, 0);
    }
  };

  stage(0, 0);
  stage(1, 1);

  #pragma unroll 1
  for (int t = 0; t < 17; ++t) {
    // tile t landed iff <= 8 loads outstanding (t+1's batch). Never drain to 0.
    asm volatile("s_waitcnt vmcnt(8)" ::: "memory");
    SCHED_FENCE();
    __builtin_amdgcn_s_barrier();
    SCHED_FENCE();
    compute(t & 1);
    SCHED_FENCE();
    __builtin_amdgcn_s_barrier();   // all waves done reading buf[t&1]
    SCHED_FENCE();
    if (t < 16) stage(t & 1, t + 2);
  }
  asm volatile("s_waitcnt vmcnt(0)" ::: "memory");
  SCHED_FENCE();
  __builtin_amdgcn_s_barrier();
  SCHED_FENCE();
  compute(1);   // tile 17 in buffer 1

  if (STATS) {
    // sb aliases buf0 (last read at t=16, fenced by t=17 entry barrier)
    float* sb = (float*)smem;      // [8 waves][64 cols] sums; sumsq at +512
    #pragma unroll
    for (int in = 0; in < 4; ++in) {
      float s = 0.f, q = 0.f;
      #pragma unroll
      for (int im = 0; im < 8; ++im)
        #pragma unroll
        for (int j = 0; j < 4; ++j) {
          const float v = acc[im][in][j];
          s += v; q += v * v;
        }
      s += __shfl_xor(s, 16); q += __shfl_xor(q, 16);
      s += __shfl_xor(s, 32); q += __shfl_xor(q, 32);
      if (lane < 16) {
        sb[wid * 64 + in * 16 + lane] = s;
        sb[512 + wid * 64 + in * 16 + lane] = q;
      }
    }
    __syncthreads();
    if (tid < 256) {
      const int wn2 = tid >> 6, cl = tid & 63;
      const float s = sb[wn2 * 64 + cl] + sb[(4 + wn2) * 64 + cl];
      const float q = sb[512 + wn2 * 64 + cl] + sb[512 + (4 + wn2) * 64 + cl];
      psum[bm * 256 + tid] = s;
      psq[bm * 256 + tid] = q;
    }
  } else {
    float bval[4];
    #pragma unroll
    for (int in = 0; in < 4; ++in)
      bval[in] = bias[wn * 64 + in * 16 + l16];
    #pragma unroll
    for (int im = 0; im < 8; ++im) {
      #pragma unroll
      for (int j = 0; j < 4; ++j) {
        const int pix = bm * 256 + wm * 128 + im * 16 + rsub * 4 + j;
        #pragma unroll
        for (int in = 0; in < 4; ++in) {
          const int f = wn * 64 + in * 16 + l16;
          out[pix * 256 + f] = fmaxf(acc[im][in][j] + bval[in], 0.f);
        }
      }
    }
  }
}

// per-channel stats: one block per channel
__global__ __launch_bounds__(256)
void kstats(const float* __restrict__ psum, const float* __restrict__ psq,
            const float* __restrict__ gamma, const float* __restrict__ beta,
            float* __restrict__ scale, float* __restrict__ bias)
{
  const int ch = blockIdx.x;
  float s = 0.f, q = 0.f;
  for (int bm = threadIdx.x; bm < MTILES; bm += 256) {
    s += psum[bm * 256 + ch];
    q += psq[bm * 256 + ch];
  }
  #pragma unroll
  for (int off = 32; off > 0; off >>= 1) {
    s += __shfl_xor(s, off);
    q += __shfl_xor(q, off);
  }
  __shared__ float ss[4], sq2[4];
  const int lane = threadIdx.x & 63, w = threadIdx.x >> 6;
  if (lane == 0) { ss[w] = s; sq2[w] = q; }
  __syncthreads();
  if (threadIdx.x == 0) {
    s = ss[0] + ss[1] + ss[2] + ss[3];
    q = sq2[0] + sq2[1] + sq2[2] + sq2[3];
    const float inv = 1.0f / (float)NPIX;
    const float mean = s * inv;
    const float var = q * inv - mean * mean;
    const float istd = 1.0f / sqrtf(var + 1e-5f);
    const float g = gamma[ch];
    scale[ch] = g * istd;
    bias[ch] = beta[ch] - g * mean * istd;
  }
}

// w_fold min/max, parallel over all elements
__global__ __launch_bounds__(256)
void kwmm(const float* __restrict__ W, const float* __restrict__ scale,
          unsigned* __restrict__ enc)
{
  const int idx = blockIdx.x * 256 + threadIdx.x;
  float v = 0.f;
  if (idx < NWELEM) v = W[idx] * scale[idx & 255];   // last dim of W is f (256)
  float mn = v, mx = v;
  #pragma unroll
  for (int off = 32; off > 0; off >>= 1) {
    mn = fminf(mn, __shfl_xor(mn, off));
    mx = fmaxf(mx, __shfl_xor(mx, off));
  }
  __shared__ float rmn[4], rmx[4];
  const int lane = threadIdx.x & 63, w = threadIdx.x >> 6;
  if (lane == 0) { rmn[w] = mn; rmx[w] = mx; }
  __syncthreads();
  if (threadIdx.x == 0) {
    mn = fminf(fminf(rmn[0], rmn[1]), fminf(rmn[2], rmn[3]));
    mx = fmaxf(fmaxf(rmx[0], rmx[1]), fmaxf(rmx[2], rmx[3]));
    atomicMin(&enc[2], encf(mn));
    atomicMax(&enc[3], encf(mx));
  }
}

extern "C" void kernel_launch(void* const* d_in, const int* in_sizes, int n_in,
                              void* d_out, int out_size, void* d_ws, size_t ws_size,
                              hipStream_t stream)
{
  const float* x     = (const float*)d_in[0];
  const float* W     = (const float*)d_in[1];
  const float* gamma = (const float*)d_in[2];
  const float* beta  = (const float*)d_in[3];
  float* out = (float*)d_out;
  char* ws = (char*)d_ws;

  unsigned* enc        = (unsigned*)(ws + OFF_ENC);
  float* scale         = (float*)(ws + OFF_SCALE);
  float* bias          = (float*)(ws + OFF_BIAS);
  unsigned short* Wt   = (unsigned short*)(ws + OFF_WT);
  unsigned short* Wqt  = (unsigned short*)(ws + OFF_WQT);
  float* psum          = (float*)(ws + OFF_PSUM);
  float* psq           = (float*)(ws + OFF_PSQ);
  unsigned short* xpad  = (unsigned short*)(ws + OFF_XPAD);
  unsigned short* xqpad = (unsigned short*)(ws + OFF_XQPAD);

  kinit<<<1, 64, 0, stream>>>(enc);
  kminmax<<<1024, 256, 0, stream>>>((const float4*)x, enc);
  kwconv<<<1152, 256, 0, stream>>>(W, Wt);
  kpadfill<<<6728, 256, 0, stream>>>(x, enc, xpad, xqpad);
  kconv<1><<<MTILES, 512, 0, stream>>>(xpad, Wt, nullptr, nullptr, psum, psq);
  kstats<<<256, 256, 0, stream>>>(psum, psq, gamma, beta, scale, bias);
  kwmm<<<1152, 256, 0, stream>>>(W, scale, enc);
  kwq<<<1152, 256, 0, stream>>>(W, scale, enc, Wqt);
  kconv<0><<<MTILES, 512, 0, stream>>>(xqpad, Wqt, out, bias, nullptr, nullptr);
}